// Round 5
// baseline (604.541 us; speedup 1.0000x reference)
//
#include <hip/hip_runtime.h>
#include <stdint.h>

typedef __bf16 bf16_t;
typedef __attribute__((ext_vector_type(8))) __bf16 bf16x8;
typedef __attribute__((ext_vector_type(4))) float f32x4;
typedef __attribute__((ext_vector_type(8))) unsigned short ushort8;
typedef __attribute__((ext_vector_type(4))) unsigned short us4;
typedef __attribute__((ext_vector_type(4))) int int4v;
typedef __attribute__((ext_vector_type(4))) float float4v;

typedef const void __attribute__((address_space(1)))* gptr_t;
typedef void __attribute__((address_space(3)))* lptr_t;

__constant__ float NF4_CB[16] = {
    -1.0f, -0.6961928009986877f, -0.5250730514526367f, -0.39491748809814453f,
    -0.28444138169288635f, -0.18477343022823334f, -0.09105003625154495f, 0.0f,
    0.07958029955625534f, 0.16093020141124725f, 0.24611230194568634f,
    0.33791524171829224f, 0.44070982933044434f, 0.5626170039176941f,
    0.6848514676094055f, 1.0f};

__device__ __forceinline__ unsigned short f32_to_bf16_rne(float f) {
    unsigned int u = __float_as_uint(f);
    u += 0x7FFFu + ((u >> 16) & 1u);
    return (unsigned short)(u >> 16);
}

// ---------------------------------------------------------------------------
// Coalesced grid-stride prep (byte-identical to R4). MEASUREMENT ROUND:
// launched 3x (idempotent) so dur_us(R5) - dur_us(R4) ~= 2 x prep_time.
// Discriminates: (A) prep ~230us for unknown reason  vs  (B) prep ~60us and
// ~180us of the per-iteration time is harness reset/memset overhead.
// ---------------------------------------------------------------------------
__global__ __launch_bounds__(256) void prep_kernel2(
        const int* __restrict__ w_codes, const float* __restrict__ w_absmax,
        const float* __restrict__ x,
        const int* __restrict__ b_codes, const float* __restrict__ b_absmax,
        unsigned short* __restrict__ outW, unsigned short* __restrict__ outA,
        float* __restrict__ outBias,
        long nW4, long nX4, long nBias) {
    __shared__ float cb[16];
    if (threadIdx.x < 16) cb[threadIdx.x] = NF4_CB[threadIdx.x];
    __syncthreads();

    const long total = nW4 + nX4 + nBias;
    const long stride = (long)gridDim.x * blockDim.x;
    for (long u = (long)blockIdx.x * blockDim.x + threadIdx.x; u < total;
         u += stride) {
        if (u < nW4) {
            int4v c = *(const int4v*)(w_codes + u * 4);
            float am = w_absmax[u >> 4];          // 16 units / 64-elem block
            us4 v;
            v[0] = f32_to_bf16_rne(cb[c[0]] * am);
            v[1] = f32_to_bf16_rne(cb[c[1]] * am);
            v[2] = f32_to_bf16_rne(cb[c[2]] * am);
            v[3] = f32_to_bf16_rne(cb[c[3]] * am);
            *(us4*)(outW + u * 4) = v;
        } else if (u < nW4 + nX4) {
            long i = u - nW4;
            float4v f = *(const float4v*)(x + i * 4);
            us4 v;
            v[0] = f32_to_bf16_rne(f[0]);
            v[1] = f32_to_bf16_rne(f[1]);
            v[2] = f32_to_bf16_rne(f[2]);
            v[3] = f32_to_bf16_rne(f[3]);
            *(us4*)(outA + i * 4) = v;
        } else {
            long o = u - nW4 - nX4;
            outBias[o] = cb[b_codes[o]] * b_absmax[o >> 6];
        }
    }
}

// ---------------------------------------------------------------------------
// Session-verified main gemm (R0, ~250 us): 256x128 tile, BK=64, 512 threads
// (8 waves, 4x2 of 64x64), 16x16x32 MFMA, XOR-swizzled LDS, glds width=16,
// single-buffered 48 KB LDS -> 3 blocks/CU; inter-block overlap gives 51%
// MfmaUtil. Byte-identical; do not touch the sync structure.
// ---------------------------------------------------------------------------
__global__ __launch_bounds__(512) void gemm_bias_kernel_256(
        const bf16_t* __restrict__ A, const bf16_t* __restrict__ B,
        const float* __restrict__ bias, float* __restrict__ C,
        int M, int N, int K) {
    __shared__ __align__(16) bf16_t sAB[24576];   // 48 KB

    const int t = threadIdx.x;
    const int lane = t & 63;
    const int wave = t >> 6;                      // 0..7
    const int tileM = blockIdx.y * 256;
    const int tileN = blockIdx.x * 128;

    const int rloc = lane >> 3;
    const int jsw  = (lane & 7) ^ rloc;
    const bf16_t* srcp[6];
    bf16_t* dstp[6];
#pragma unroll
    for (int j = 0; j < 6; ++j) {
        int c = wave * 6 + j;
        int isB = (c >= 32);
        int r = (isB ? (c - 32) : c) * 8 + rloc;
        const bf16_t* base = isB ? (B + (size_t)(tileN + r) * K)
                                 : (A + (size_t)(tileM + r) * K);
        srcp[j] = base + jsw * 8;
        dstp[j] = &sAB[c * 512 + lane * 8];
    }

    const int wm = wave >> 1;
    const int wn = wave & 1;
    const int la = lane & 15;
    const int jA = lane >> 4;
    const int jj0 = (jA ^ (lane & 7)) * 8;
    const int aoff = (wm * 64 + la) * 64 + jj0;
    const int boff = 16384 + (wn * 64 + la) * 64 + jj0;

    f32x4 acc[4][4] = {};

    for (int kt = 0; kt < K; kt += 64) {
#pragma unroll
        for (int j = 0; j < 6; ++j) {
            __builtin_amdgcn_global_load_lds((gptr_t)(srcp[j]), (lptr_t)(dstp[j]),
                                             16, 0, 0);
            srcp[j] += 64;
        }
        __syncthreads();

#pragma unroll
        for (int kh = 0; kh < 2; ++kh) {
            const int kx = kh * 32;
            bf16x8 a[4], b[4];
#pragma unroll
            for (int i = 0; i < 4; ++i) a[i] = *(const bf16x8*)&sAB[(aoff + i * 1024) ^ kx];
#pragma unroll
            for (int i = 0; i < 4; ++i) b[i] = *(const bf16x8*)&sAB[(boff + i * 1024) ^ kx];
#pragma unroll
            for (int mi = 0; mi < 4; ++mi)
#pragma unroll
                for (int ni = 0; ni < 4; ++ni)
                    acc[mi][ni] = __builtin_amdgcn_mfma_f32_16x16x32_bf16(
                        a[mi], b[ni], acc[mi][ni], 0, 0, 0);
        }
        __syncthreads();
    }

    const int col0 = tileN + wn * 64 + la;
    const int row0 = tileM + wm * 64 + jA * 4;
    float bv[4];
#pragma unroll
    for (int ni = 0; ni < 4; ++ni) bv[ni] = bias[col0 + ni * 16];
#pragma unroll
    for (int mi = 0; mi < 4; ++mi)
#pragma unroll
        for (int ni = 0; ni < 4; ++ni)
#pragma unroll
            for (int r = 0; r < 4; ++r)
                C[(size_t)(row0 + mi * 16 + r) * N + (col0 + ni * 16)] =
                    acc[mi][ni][r] + bv[ni];
}

// Fallback: 128x128 tile, 256 threads (used only if M % 256 != 0).
__global__ void gemm_bias_kernel_128(const bf16_t* __restrict__ A,
                                     const bf16_t* __restrict__ B,
                                     const float* __restrict__ bias,
                                     float* __restrict__ C,
                                     int M, int N, int K) {
    __shared__ __align__(16) bf16_t sAB[16384];
    const int t = threadIdx.x;
    const int lane = t & 63;
    const int wave = t >> 6;
    const int tileM = blockIdx.y * 128;
    const int tileN = blockIdx.x * 128;

    const int rloc = lane >> 3;
    const int jsw  = (lane & 7) ^ rloc;
    const int chunk0 = wave * 8;
    const int isB = chunk0 >> 4;
    const int ci0 = chunk0 & 15;
    const int r0 = ci0 * 8 + rloc;
    const bf16_t* srcp = (isB ? (B + (size_t)(tileN + r0) * K)
                              : (A + (size_t)(tileM + r0) * K)) + jsw * 8;
    bf16_t* dstp = &sAB[isB * 8192 + ci0 * 512 + lane * 8];
    const size_t srcChunkStride = (size_t)8 * K;

    const int wm = wave >> 1;
    const int wn = wave & 1;
    const int la = lane & 15;
    const int jA = lane >> 4;
    const int jj0 = (jA ^ (lane & 7)) * 8;
    const int aoff = (wm * 64 + la) * 64 + jj0;
    const int boff = 8192 + (wn * 64 + la) * 64 + jj0;

    f32x4 acc[4][4] = {};
    for (int kt = 0; kt < K; kt += 64) {
#pragma unroll
        for (int j8 = 0; j8 < 8; ++j8)
            __builtin_amdgcn_global_load_lds((gptr_t)(srcp + j8 * srcChunkStride),
                                             (lptr_t)(dstp + j8 * 512), 16, 0, 0);
        srcp += 64;
        __syncthreads();
#pragma unroll
        for (int kh = 0; kh < 2; ++kh) {
            const int kx = kh * 32;
            bf16x8 a[4], b[4];
#pragma unroll
            for (int i = 0; i < 4; ++i) a[i] = *(const bf16x8*)&sAB[(aoff + i * 1024) ^ kx];
#pragma unroll
            for (int i = 0; i < 4; ++i) b[i] = *(const bf16x8*)&sAB[(boff + i * 1024) ^ kx];
#pragma unroll
            for (int mi = 0; mi < 4; ++mi)
#pragma unroll
                for (int ni = 0; ni < 4; ++ni)
                    acc[mi][ni] = __builtin_amdgcn_mfma_f32_16x16x32_bf16(
                        a[mi], b[ni], acc[mi][ni], 0, 0, 0);
        }
        __syncthreads();
    }
    const int col0 = tileN + wn * 64 + la;
    const int row0 = tileM + wm * 64 + jA * 4;
    float bv[4];
#pragma unroll
    for (int ni = 0; ni < 4; ++ni) bv[ni] = bias[col0 + ni * 16];
#pragma unroll
    for (int mi = 0; mi < 4; ++mi)
#pragma unroll
        for (int ni = 0; ni < 4; ++ni)
#pragma unroll
            for (int r = 0; r < 4; ++r)
                C[(size_t)(row0 + mi * 16 + r) * N + (col0 + ni * 16)] =
                    acc[mi][ni][r] + bv[ni];
}

extern "C" void kernel_launch(void* const* d_in, const int* in_sizes, int n_in,
                              void* d_out, int out_size, void* d_ws, size_t ws_size,
                              hipStream_t stream) {
    const float* x        = (const float*)d_in[0];
    const int*   w_codes  = (const int*)d_in[1];
    const float* w_absmax = (const float*)d_in[2];
    const int*   b_codes  = (const int*)d_in[3];
    const float* b_absmax = (const float*)d_in[4];
    float* out = (float*)d_out;

    const int  D_OUT = in_sizes[3];
    const long WK    = (long)in_sizes[1];
    const int  D_IN  = (int)(WK / D_OUT);
    const long xN    = (long)in_sizes[0];
    const int  M     = (int)(xN / D_IN);
    const int  N = D_OUT, K = D_IN;

    unsigned short* wsW = (unsigned short*)d_ws;
    unsigned short* wsA = wsW + (size_t)N * K;
    float* wsBias = (float*)(wsA + (size_t)M * K);

    long nW4 = WK / 4;
    long nX4 = xN / 4;
    long nBias = D_OUT;
    long totalUnits = nW4 + nX4 + nBias;
    long nblk = (totalUnits + 255) / 256;
    if (nblk > 2048) nblk = 2048;

    // MEASUREMENT: 3 identical, idempotent prep launches.
    // dur_us(this) - dur_us(R4) ~= 2 x prep_time. See theory for the
    // pre-committed interpretation.
    for (int rep = 0; rep < 3; ++rep) {
        prep_kernel2<<<dim3((unsigned)nblk), dim3(256), 0, stream>>>(
            w_codes, w_absmax, x, b_codes, b_absmax, wsW, wsA, wsBias,
            nW4, nX4, nBias);
    }

    if (M % 256 == 0) {
        gemm_bias_kernel_256<<<dim3(N / 128, M / 256), dim3(512), 0, stream>>>(
            (const bf16_t*)wsA, (const bf16_t*)wsW, wsBias, out, M, N, K);
    } else {
        gemm_bias_kernel_128<<<dim3(N / 128, M / 128), dim3(256), 0, stream>>>(
            (const bf16_t*)wsA, (const bf16_t*)wsW, wsBias, out, M, N, K);
    }
}

// Round 6
// 492.348 us; speedup vs baseline: 1.2279x; 1.2279x over previous
//
#include <hip/hip_runtime.h>
#include <stdint.h>

typedef __bf16 bf16_t;
typedef __attribute__((ext_vector_type(8))) __bf16 bf16x8;
typedef __attribute__((ext_vector_type(4))) float f32x4;
typedef __attribute__((ext_vector_type(4))) unsigned short us4;
typedef __attribute__((ext_vector_type(4))) int int4v;
typedef __attribute__((ext_vector_type(4))) float float4v;

typedef const void __attribute__((address_space(1)))* gptr_t;
typedef void __attribute__((address_space(3)))* lptr_t;

__constant__ float NF4_CB[16] = {
    -1.0f, -0.6961928009986877f, -0.5250730514526367f, -0.39491748809814453f,
    -0.28444138169288635f, -0.18477343022823334f, -0.09105003625154495f, 0.0f,
    0.07958029955625534f, 0.16093020141124725f, 0.24611230194568634f,
    0.33791524171829224f, 0.44070982933044434f, 0.5626170039176941f,
    0.6848514676094055f, 1.0f};

__device__ __forceinline__ unsigned short f32_to_bf16_rne(float f) {
    unsigned int u = __float_as_uint(f);
    u += 0x7FFFu + ((u >> 16) & 1u);
    return (unsigned short)(u >> 16);
}

// Coalesced grid-stride prep (R4-verified, ~49 us = BW floor). 1x launch.
__global__ __launch_bounds__(256) void prep_kernel2(
        const int* __restrict__ w_codes, const float* __restrict__ w_absmax,
        const float* __restrict__ x,
        const int* __restrict__ b_codes, const float* __restrict__ b_absmax,
        unsigned short* __restrict__ outW, unsigned short* __restrict__ outA,
        float* __restrict__ outBias,
        long nW4, long nX4, long nBias) {
    __shared__ float cb[16];
    if (threadIdx.x < 16) cb[threadIdx.x] = NF4_CB[threadIdx.x];
    __syncthreads();

    const long total = nW4 + nX4 + nBias;
    const long stride = (long)gridDim.x * blockDim.x;
    for (long u = (long)blockIdx.x * blockDim.x + threadIdx.x; u < total;
         u += stride) {
        if (u < nW4) {
            int4v c = *(const int4v*)(w_codes + u * 4);
            float am = w_absmax[u >> 4];
            us4 v;
            v[0] = f32_to_bf16_rne(cb[c[0]] * am);
            v[1] = f32_to_bf16_rne(cb[c[1]] * am);
            v[2] = f32_to_bf16_rne(cb[c[2]] * am);
            v[3] = f32_to_bf16_rne(cb[c[3]] * am);
            *(us4*)(outW + u * 4) = v;
        } else if (u < nW4 + nX4) {
            long i = u - nW4;
            float4v f = *(const float4v*)(x + i * 4);
            us4 v;
            v[0] = f32_to_bf16_rne(f[0]);
            v[1] = f32_to_bf16_rne(f[1]);
            v[2] = f32_to_bf16_rne(f[2]);
            v[3] = f32_to_bf16_rne(f[3]);
            *(us4*)(outA + i * 4) = v;
        } else {
            long o = u - nW4 - nX4;
            outBias[o] = cb[b_codes[o]] * b_absmax[o >> 6];
        }
    }
}

// ---------------------------------------------------------------------------
// 256x256 / BK=64 / 512 threads (8 waves = 2M x 4N, 128x64 out each),
// double-buffered 128 KiB LDS, 4 fine phases per K-tile:
//   phase = (m-half, k-half) in order (0,0)(1,0)(1,1)(0,1); 16 MFMA each;
//   per phase 4-8 ds_read_b128 (b-regs live <= 1 phase; a phase-local);
//   2 fenced raw barriers per phase (m201 count); setprio around MFMA.
// Staging: tile t+1's 8 global_load_lds issued 4+4 in ph0/ph1 of tile t
//   into buf[1^cur] (freed at t-1's final barrier -> WAR-safe, same argument
//   as harness-passed R1); drain vmcnt(0) at END of ph3 when the newest
//   load is ~2 phases old -> wait is near-free (issue-early / wait-late).
// ds_read -> MFMA ordering is left to the compiler (C++ LDS reads, no
//   inline-asm lgkm). Staging/swizzle/fragment/epilogue formulas are R1's
//   harness-verified ones, byte-for-byte.
// ---------------------------------------------------------------------------
#define FENCE() asm volatile("" ::: "memory")
#define BAR() do { FENCE(); __builtin_amdgcn_s_barrier(); FENCE(); } while (0)

#define READ_A(dst, H, KH, BASE) do { \
  _Pragma("unroll") for (int i_ = 0; i_ < 4; ++i_) \
    dst[i_] = *(const bf16x8*)&sAB[((aoff + (4*(H) + i_) * 1024) ^ ((KH) << 5)) + (BASE)]; \
} while (0)

#define READ_B(dst, KH, BASE) do { \
  _Pragma("unroll") for (int i_ = 0; i_ < 4; ++i_) \
    dst[i_] = *(const bf16x8*)&sAB[((boff + i_ * 1024) ^ ((KH) << 5)) + (BASE)]; \
} while (0)

#define MFMA16(areg, breg, H) do { \
  __builtin_amdgcn_s_setprio(1); \
  _Pragma("unroll") for (int mi_ = 0; mi_ < 4; ++mi_) \
    _Pragma("unroll") for (int ni_ = 0; ni_ < 4; ++ni_) \
      acc[4*(H) + mi_][ni_] = __builtin_amdgcn_mfma_f32_16x16x32_bf16( \
          areg[mi_], breg[ni_], acc[4*(H) + mi_][ni_], 0, 0, 0); \
  __builtin_amdgcn_s_setprio(0); \
} while (0)

#define STAGE4(J0, SDST) do { \
  _Pragma("unroll") for (int j_ = 0; j_ < 4; ++j_) { \
    __builtin_amdgcn_global_load_lds((gptr_t)srcp[(J0) + j_], \
        (lptr_t)((SDST) + ((J0) + j_) * 512), 16, 0, 0); \
    srcp[(J0) + j_] += 64; \
  } \
} while (0)

__global__ __launch_bounds__(512, 2) void gemm_bias_kernel_256x256_ph(
        const bf16_t* __restrict__ A, const bf16_t* __restrict__ B,
        const float* __restrict__ bias, float* __restrict__ C,
        int M, int N, int K) {
    __shared__ __align__(16) bf16_t sAB[65536];   // 128 KiB, 2 x (A 32KB + B 32KB)

    const int t = threadIdx.x;
    const int lane = t & 63;
    const int wave = t >> 6;                      // 0..7

    // Bijective XCD swizzle (nwg % 8 == 0 here; identity otherwise).
    const int nbx = gridDim.x;
    const int nwg = nbx * (int)gridDim.y;
    int flat = (int)blockIdx.y * nbx + (int)blockIdx.x;
    if ((nwg & 7) == 0) flat = (flat & 7) * (nwg >> 3) + (flat >> 3);
    const int tileM = (flat / nbx) * 256;
    const int tileN = (flat % nbx) * 256;

    // ---- staging addresses (R1 harness-verified formulas) ----
    const int rloc = lane >> 3;
    const int jsw  = (lane & 7) ^ rloc;
    const bf16_t* srcp[8];
#pragma unroll
    for (int j = 0; j < 8; ++j) {
        int c = wave * 8 + j;                     // 0..63; 0-31 A, 32-63 B
        int isB = c >> 5;
        int r = (c & 31) * 8 + rloc;
        const bf16_t* base = isB ? (B + (size_t)(tileN + r) * K)
                                 : (A + (size_t)(tileM + r) * K);
        srcp[j] = base + jsw * 8;
    }
    bf16_t* dst0 = &sAB[wave * 4096 + lane * 8];

    // ---- fragment-read addresses (R1 harness-verified formulas) ----
    const int wm = wave >> 2;                     // 0..1
    const int wn = wave & 3;                      // 0..3
    const int la = lane & 15;
    const int jA = lane >> 4;
    const int jj0 = (jA ^ (lane & 7)) * 8;
    const int aoff = (wm * 128 + la) * 64 + jj0;
    const int boff = 16384 + (wn * 64 + la) * 64 + jj0;

    f32x4 acc[8][4] = {};
    const int nt = K >> 6;

    // Prologue: stage tile 0 into buf0, drain, barrier.
#pragma unroll
    for (int j = 0; j < 8; ++j) {
        __builtin_amdgcn_global_load_lds((gptr_t)srcp[j], (lptr_t)(dst0 + j * 512),
                                         16, 0, 0);
        srcp[j] += 64;
    }
    asm volatile("s_waitcnt vmcnt(0)" ::: "memory");
    BAR();

    for (int kt = 0; kt < nt; ++kt) {
        const int base = (kt & 1) << 15;                 // current buffer (elems)
        bf16_t* sdst = dst0 + ((((kt & 1) ^ 1)) << 15);  // next buffer
        const bool st = (kt + 1 < nt);
        bf16x8 a[4], b0[4], b1[4];

        // ph0: (m0,k0) — stage first 4 chunks of tile kt+1
        if (st) STAGE4(0, sdst);
        READ_A(a, 0, 0, base);
        READ_B(b0, 0, base);
        BAR();
        MFMA16(a, b0, 0);
        BAR();

        // ph1: (m1,k0) — stage last 4 chunks
        if (st) STAGE4(4, sdst);
        READ_A(a, 1, 0, base);
        BAR();
        MFMA16(a, b0, 1);
        BAR();

        // ph2: (m1,k1)
        READ_A(a, 1, 1, base);
        READ_B(b1, 1, base);
        BAR();
        MFMA16(a, b1, 1);
        BAR();

        // ph3: (m0,k1) — drain tile kt+1's loads (issued ph0/ph1: stale, cheap)
        READ_A(a, 0, 1, base);
        BAR();
        MFMA16(a, b1, 0);
        asm volatile("s_waitcnt vmcnt(0)" ::: "memory");
        BAR();
    }

    const int col0 = tileN + wn * 64 + la;
    const int row0 = tileM + wm * 128 + jA * 4;
    float bv[4];
#pragma unroll
    for (int ni = 0; ni < 4; ++ni) bv[ni] = bias[col0 + ni * 16];
#pragma unroll
    for (int mi = 0; mi < 8; ++mi)
#pragma unroll
        for (int ni = 0; ni < 4; ++ni)
#pragma unroll
            for (int r = 0; r < 4; ++r)
                C[(size_t)(row0 + mi * 16 + r) * N + (col0 + ni * 16)] =
                    acc[mi][ni][r] + bv[ni];
}

// Fallback: 256x128 tile, 512 threads (session-verified R0, ~250 us).
__global__ __launch_bounds__(512) void gemm_bias_kernel_256(
        const bf16_t* __restrict__ A, const bf16_t* __restrict__ B,
        const float* __restrict__ bias, float* __restrict__ C,
        int M, int N, int K) {
    __shared__ __align__(16) bf16_t sAB[24576];

    const int t = threadIdx.x;
    const int lane = t & 63;
    const int wave = t >> 6;
    const int tileM = blockIdx.y * 256;
    const int tileN = blockIdx.x * 128;

    const int rloc = lane >> 3;
    const int jsw  = (lane & 7) ^ rloc;
    const bf16_t* srcp[6];
    bf16_t* dstp[6];
#pragma unroll
    for (int j = 0; j < 6; ++j) {
        int c = wave * 6 + j;
        int isB = (c >= 32);
        int r = (isB ? (c - 32) : c) * 8 + rloc;
        const bf16_t* base = isB ? (B + (size_t)(tileN + r) * K)
                                 : (A + (size_t)(tileM + r) * K);
        srcp[j] = base + jsw * 8;
        dstp[j] = &sAB[c * 512 + lane * 8];
    }

    const int wm = wave >> 1;
    const int wn = wave & 1;
    const int la = lane & 15;
    const int jA = lane >> 4;
    const int jj0 = (jA ^ (lane & 7)) * 8;
    const int aoff = (wm * 64 + la) * 64 + jj0;
    const int boff = 16384 + (wn * 64 + la) * 64 + jj0;

    f32x4 acc[4][4] = {};

    for (int kt = 0; kt < K; kt += 64) {
#pragma unroll
        for (int j = 0; j < 6; ++j) {
            __builtin_amdgcn_global_load_lds((gptr_t)(srcp[j]), (lptr_t)(dstp[j]),
                                             16, 0, 0);
            srcp[j] += 64;
        }
        __syncthreads();

#pragma unroll
        for (int kh = 0; kh < 2; ++kh) {
            const int kx = kh * 32;
            bf16x8 a[4], b[4];
#pragma unroll
            for (int i = 0; i < 4; ++i) a[i] = *(const bf16x8*)&sAB[(aoff + i * 1024) ^ kx];
#pragma unroll
            for (int i = 0; i < 4; ++i) b[i] = *(const bf16x8*)&sAB[(boff + i * 1024) ^ kx];
#pragma unroll
            for (int mi = 0; mi < 4; ++mi)
#pragma unroll
                for (int ni = 0; ni < 4; ++ni)
                    acc[mi][ni] = __builtin_amdgcn_mfma_f32_16x16x32_bf16(
                        a[mi], b[ni], acc[mi][ni], 0, 0, 0);
        }
        __syncthreads();
    }

    const int col0 = tileN + wn * 64 + la;
    const int row0 = tileM + wm * 64 + jA * 4;
    float bv[4];
#pragma unroll
    for (int ni = 0; ni < 4; ++ni) bv[ni] = bias[col0 + ni * 16];
#pragma unroll
    for (int mi = 0; mi < 4; ++mi)
#pragma unroll
        for (int ni = 0; ni < 4; ++ni)
#pragma unroll
            for (int r = 0; r < 4; ++r)
                C[(size_t)(row0 + mi * 16 + r) * N + (col0 + ni * 16)] =
                    acc[mi][ni][r] + bv[ni];
}

// Fallback: 128x128 tile, 256 threads (used only if M % 256 != 0).
__global__ void gemm_bias_kernel_128(const bf16_t* __restrict__ A,
                                     const bf16_t* __restrict__ B,
                                     const float* __restrict__ bias,
                                     float* __restrict__ C,
                                     int M, int N, int K) {
    __shared__ __align__(16) bf16_t sAB[16384];
    const int t = threadIdx.x;
    const int lane = t & 63;
    const int wave = t >> 6;
    const int tileM = blockIdx.y * 128;
    const int tileN = blockIdx.x * 128;

    const int rloc = lane >> 3;
    const int jsw  = (lane & 7) ^ rloc;
    const int chunk0 = wave * 8;
    const int isB = chunk0 >> 4;
    const int ci0 = chunk0 & 15;
    const int r0 = ci0 * 8 + rloc;
    const bf16_t* srcp = (isB ? (B + (size_t)(tileN + r0) * K)
                              : (A + (size_t)(tileM + r0) * K)) + jsw * 8;
    bf16_t* dstp = &sAB[isB * 8192 + ci0 * 512 + lane * 8];
    const size_t srcChunkStride = (size_t)8 * K;

    const int wm = wave >> 1;
    const int wn = wave & 1;
    const int la = lane & 15;
    const int jA = lane >> 4;
    const int jj0 = (jA ^ (lane & 7)) * 8;
    const int aoff = (wm * 64 + la) * 64 + jj0;
    const int boff = 8192 + (wn * 64 + la) * 64 + jj0;

    f32x4 acc[4][4] = {};
    for (int kt = 0; kt < K; kt += 64) {
#pragma unroll
        for (int j8 = 0; j8 < 8; ++j8)
            __builtin_amdgcn_global_load_lds((gptr_t)(srcp + j8 * srcChunkStride),
                                             (lptr_t)(dstp + j8 * 512), 16, 0, 0);
        srcp += 64;
        __syncthreads();
#pragma unroll
        for (int kh = 0; kh < 2; ++kh) {
            const int kx = kh * 32;
            bf16x8 a[4], b[4];
#pragma unroll
            for (int i = 0; i < 4; ++i) a[i] = *(const bf16x8*)&sAB[(aoff + i * 1024) ^ kx];
#pragma unroll
            for (int i = 0; i < 4; ++i) b[i] = *(const bf16x8*)&sAB[(boff + i * 1024) ^ kx];
#pragma unroll
            for (int mi = 0; mi < 4; ++mi)
#pragma unroll
                for (int ni = 0; ni < 4; ++ni)
                    acc[mi][ni] = __builtin_amdgcn_mfma_f32_16x16x32_bf16(
                        a[mi], b[ni], acc[mi][ni], 0, 0, 0);
        }
        __syncthreads();
    }
    const int col0 = tileN + wn * 64 + la;
    const int row0 = tileM + wm * 64 + jA * 4;
    float bv[4];
#pragma unroll
    for (int ni = 0; ni < 4; ++ni) bv[ni] = bias[col0 + ni * 16];
#pragma unroll
    for (int mi = 0; mi < 4; ++mi)
#pragma unroll
        for (int ni = 0; ni < 4; ++ni)
#pragma unroll
            for (int r = 0; r < 4; ++r)
                C[(size_t)(row0 + mi * 16 + r) * N + (col0 + ni * 16)] =
                    acc[mi][ni][r] + bv[ni];
}

extern "C" void kernel_launch(void* const* d_in, const int* in_sizes, int n_in,
                              void* d_out, int out_size, void* d_ws, size_t ws_size,
                              hipStream_t stream) {
    const float* x        = (const float*)d_in[0];
    const int*   w_codes  = (const int*)d_in[1];
    const float* w_absmax = (const float*)d_in[2];
    const int*   b_codes  = (const int*)d_in[3];
    const float* b_absmax = (const float*)d_in[4];
    float* out = (float*)d_out;

    const int  D_OUT = in_sizes[3];
    const long WK    = (long)in_sizes[1];
    const int  D_IN  = (int)(WK / D_OUT);
    const long xN    = (long)in_sizes[0];
    const int  M     = (int)(xN / D_IN);
    const int  N = D_OUT, K = D_IN;

    unsigned short* wsW = (unsigned short*)d_ws;
    unsigned short* wsA = wsW + (size_t)N * K;
    float* wsBias = (float*)(wsA + (size_t)M * K);

    long nW4 = WK / 4;
    long nX4 = xN / 4;
    long nBias = D_OUT;
    long totalUnits = nW4 + nX4 + nBias;
    long nblk = (totalUnits + 255) / 256;
    if (nblk > 2048) nblk = 2048;
    prep_kernel2<<<dim3((unsigned)nblk), dim3(256), 0, stream>>>(
        w_codes, w_absmax, x, b_codes, b_absmax, wsW, wsA, wsBias,
        nW4, nX4, nBias);

    if (M % 256 == 0 && N % 256 == 0 && K % 64 == 0) {
        gemm_bias_kernel_256x256_ph<<<dim3(N / 256, M / 256), dim3(512), 0, stream>>>(
            (const bf16_t*)wsA, (const bf16_t*)wsW, wsBias, out, M, N, K);
    } else if (M % 256 == 0) {
        gemm_bias_kernel_256<<<dim3(N / 128, M / 256), dim3(512), 0, stream>>>(
            (const bf16_t*)wsA, (const bf16_t*)wsW, wsBias, out, M, N, K);
    } else {
        gemm_bias_kernel_128<<<dim3(N / 128, M / 128), dim3(256), 0, stream>>>(
            (const bf16_t*)wsA, (const bf16_t*)wsW, wsBias, out, M, N, K);
    }
}